// Round 6
// baseline (177.967 us; speedup 1.0000x reference)
//
#include <hip/hip_runtime.h>

// ---------------------------------------------------------------------------
// DiscriminatorMBD, fp32 end-to-end except GEMM (bf16x3 MFMA, ~1e-6 rel err):
//  kP: prep — conv2 weight transform ws2[ic][tap][slot64]; T -> bf16 hi/lo
//  kC: fused conv1+relu+pool + conv2+relu+pool (1 image/block, 512 blocks)
//      -> feats f32 [512][640] and bf16 hi/lo copies
//  k3m: M = feats @ T^T via mfma_f32_16x16x32_bf16 (x3 split), direct-from-
//       global fragments (no LDS, no barriers), 512 blocks
//  k4: partial closeness over j-quarters -> cp[16][512][64]
//  k5: concat + fc1 + relu + fc2 + sigmoid -> out[512]
// ---------------------------------------------------------------------------

typedef __attribute__((ext_vector_type(8))) short bf16x8;
typedef __attribute__((ext_vector_type(4))) float f32x4;

static __device__ __forceinline__ unsigned short f2bf(float x) {
  unsigned int u = __float_as_uint(x);
  unsigned int r = (u + 0x7fffu + ((u >> 16) & 1u)) >> 16;
  return (unsigned short)r;
}
static __device__ __forceinline__ float bf2f(unsigned short h) {
  return __uint_as_float(((unsigned int)h) << 16);
}

// ---- kP: weight transform + T bf16 split ----------------------------------
// ws2 flat: ((ic*25 + tap)*64 + grp*8 + q), oc = grp*5+q (q<5 valid, else 0)
__global__ __launch_bounds__(256) void kP_prep(
    const float* __restrict__ c2w, const float* __restrict__ T,
    float* __restrict__ ws2, unsigned short* __restrict__ Th,
    unsigned short* __restrict__ Tl) {
  const int idx = blockIdx.x * 256 + threadIdx.x;
  if (idx < 655360) {
    const float v = T[idx];
    const unsigned short h = f2bf(v);
    Th[idx] = h;
    Tl[idx] = f2bf(v - bf2f(h));
  }
  if (idx < 32000) {
    const int ic = idx / 1600;
    const int r = idx - ic * 1600;
    const int tap = r >> 6;
    const int slot = r & 63;
    const int grp = slot >> 3;
    const int q = slot & 7;
    float val = 0.f;
    if (q < 5) val = c2w[(grp * 5 + q) * 500 + ic * 25 + tap];
    ws2[idx] = val;
  }
}

// ---- kC: fused conv1+pool -> conv2+pool, 1 image/block --------------------
// 512 blocks x 256 thr (2 blocks/CU, 8 waves/CU).
// conv1: 720 quads over 256 thr. conv2: thread = (h=ic-half, grp 0..7 of
// 5 oc, pos 0..15 pooled output); 20 accs, 500 FMA per ic, 10 ics.
__global__ __launch_bounds__(256) void kC_conv(
    const float* __restrict__ x, const float* __restrict__ c1w,
    const float* __restrict__ c1b, const float* __restrict__ ws2,
    const float* __restrict__ c2b, float* __restrict__ feats,
    unsigned short* __restrict__ fh, unsigned short* __restrict__ fl) {
  __shared__ __align__(16) float img[784];
  __shared__ __align__(16) float h1s[2880];
  __shared__ float wl1[500];
  __shared__ float bl1[20];
  __shared__ float bl2[40];
  __shared__ __align__(16) float wl2[2][2][1600];  // [ic-stream][parity][tap*64+slot]
  __shared__ float mg[128][21];

  const int tid = threadIdx.x;
  const int imgId = blockIdx.x;

  {  // stage image + conv1 weights + biases
    float4* dst = reinterpret_cast<float4*>(img);
    const float4* src = reinterpret_cast<const float4*>(x + imgId * 784);
    for (int t = tid; t < 196; t += 256) dst[t] = src[t];
  }
  for (int t = tid; t < 500; t += 256) wl1[t] = c1w[t];
  if (tid < 20) bl1[tid] = c1b[tid];
  if (tid >= 64 && tid < 104) bl2[tid - 64] = c2b[tid - 64];
  __syncthreads();

  // ---- conv1: 720 quads (ch, 2-row band, 4 pooled outputs) ----
  for (int qd = tid; qd < 720; qd += 256) {
    const int ch = qd / 36;
    const int rem = qd - ch * 36;
    const int py = rem / 3;
    const int qx = rem - py * 3;
    const int r0 = py * 2;
    const int c0 = qx * 8;
    float p[6][12];
#pragma unroll
    for (int r = 0; r < 6; ++r) {
      const float* ib = &img[(r0 + r) * 28 + c0];
      const float4 a = *reinterpret_cast<const float4*>(ib);
      const float4 b = *reinterpret_cast<const float4*>(ib + 4);
      const float4 c = *reinterpret_cast<const float4*>(ib + 8);
      p[r][0] = a.x; p[r][1] = a.y; p[r][2] = a.z; p[r][3] = a.w;
      p[r][4] = b.x; p[r][5] = b.y; p[r][6] = b.z; p[r][7] = b.w;
      p[r][8] = c.x; p[r][9] = c.y; p[r][10] = c.z; p[r][11] = c.w;
    }
    float s[16];
#pragma unroll
    for (int u = 0; u < 16; ++u) s[u] = 0.f;
    const float* wc = &wl1[ch * 25];
#pragma unroll
    for (int ky = 0; ky < 5; ++ky) {
#pragma unroll
      for (int kx = 0; kx < 5; ++kx) {
        const float w = wc[ky * 5 + kx];
#pragma unroll
        for (int u = 0; u < 4; ++u) {
#pragma unroll
          for (int dy = 0; dy < 2; ++dy) {
#pragma unroll
            for (int dx = 0; dx < 2; ++dx) {
              s[u * 4 + dy * 2 + dx] += p[ky + dy][2 * u + dx + kx] * w;
            }
          }
        }
      }
    }
    const float bb = bl1[ch];
    float4 o;
    o.x = fmaxf(fmaxf(fmaxf(s[0], s[1]), fmaxf(s[2], s[3])) + bb, 0.f);
    o.y = fmaxf(fmaxf(fmaxf(s[4], s[5]), fmaxf(s[6], s[7])) + bb, 0.f);
    o.z = fmaxf(fmaxf(fmaxf(s[8], s[9]), fmaxf(s[10], s[11])) + bb, 0.f);
    o.w = fmaxf(fmaxf(fmaxf(s[12], s[13]), fmaxf(s[14], s[15])) + bb, 0.f);
    *reinterpret_cast<float4*>(&h1s[ch * 144 + py * 12 + qx * 4]) = o;
  }

  // ---- initial conv2 weight stage (parity 0): ic = 0 and ic = 10 ----
  float4* wlf4 = reinterpret_cast<float4*>(&wl2[0][0][0]);
  const float4* wsf4 = reinterpret_cast<const float4*>(ws2);
#pragma unroll
  for (int k = 0; k < 4; ++k) {
    const int e = tid + k * 256;
    if (e < 800) {
      const int str = e / 400;
      const int i4 = e - str * 400;
      wlf4[(str * 2 + 0) * 400 + i4] = wsf4[(str * 10 + 0) * 400 + i4];
    }
  }
  __syncthreads();

  // ---- conv2: 10 stages, double-buffered weights ----
  const int h = tid >> 7;         // ic-half
  const int grp = (tid >> 4) & 7; // 5-oc group
  const int pos = tid & 15;       // pooled output
  const int oy = (pos >> 2) * 2;
  const int ox = (pos & 3) * 2;
  float acc[5][4];
#pragma unroll
  for (int q = 0; q < 5; ++q)
#pragma unroll
    for (int u = 0; u < 4; ++u) acc[q][u] = 0.f;

  for (int s = 0; s < 10; ++s) {
    const int p0 = s & 1;
    float4 sv[4];
    if (s < 9) {  // early global loads for next stage
#pragma unroll
      for (int k = 0; k < 4; ++k) {
        const int e = tid + k * 256;
        if (e < 800) {
          const int str = e / 400;
          const int i4 = e - str * 400;
          sv[k] = wsf4[(str * 10 + s + 1) * 400 + i4];
        }
      }
    }
    const int ic = h * 10 + s;
    float p[6][6];
    {
      const float* ib = &h1s[ic * 144 + oy * 12 + ox];
#pragma unroll
      for (int r = 0; r < 6; ++r) {
        const float2 v0 = *reinterpret_cast<const float2*>(&ib[r * 12 + 0]);
        const float2 v1 = *reinterpret_cast<const float2*>(&ib[r * 12 + 2]);
        const float2 v2 = *reinterpret_cast<const float2*>(&ib[r * 12 + 4]);
        p[r][0] = v0.x; p[r][1] = v0.y; p[r][2] = v1.x;
        p[r][3] = v1.y; p[r][4] = v2.x; p[r][5] = v2.y;
      }
    }
    const float* wbase = &wl2[h][p0][0];
#pragma unroll
    for (int ky = 0; ky < 5; ++ky) {
#pragma unroll
      for (int kx = 0; kx < 5; ++kx) {
        const int tap = ky * 5 + kx;
        const float4 w4 =
            *reinterpret_cast<const float4*>(&wbase[tap * 64 + grp * 8]);
        const float w4b = wbase[tap * 64 + grp * 8 + 4];
        const float i00 = p[ky][kx];
        const float i01 = p[ky][kx + 1];
        const float i10 = p[ky + 1][kx];
        const float i11 = p[ky + 1][kx + 1];
        acc[0][0] += i00 * w4.x; acc[0][1] += i01 * w4.x;
        acc[0][2] += i10 * w4.x; acc[0][3] += i11 * w4.x;
        acc[1][0] += i00 * w4.y; acc[1][1] += i01 * w4.y;
        acc[1][2] += i10 * w4.y; acc[1][3] += i11 * w4.y;
        acc[2][0] += i00 * w4.z; acc[2][1] += i01 * w4.z;
        acc[2][2] += i10 * w4.z; acc[2][3] += i11 * w4.z;
        acc[3][0] += i00 * w4.w; acc[3][1] += i01 * w4.w;
        acc[3][2] += i10 * w4.w; acc[3][3] += i11 * w4.w;
        acc[4][0] += i00 * w4b; acc[4][1] += i01 * w4b;
        acc[4][2] += i10 * w4b; acc[4][3] += i11 * w4b;
      }
    }
    if (s < 9) {  // late LDS writes into other parity
#pragma unroll
      for (int k = 0; k < 4; ++k) {
        const int e = tid + k * 256;
        if (e < 800) {
          const int str = e / 400;
          const int i4 = e - str * 400;
          wlf4[(str * 2 + ((s + 1) & 1)) * 400 + i4] = sv[k];
        }
      }
    }
    __syncthreads();
  }

  // ---- merge ic-halves, pool, relu, write feats (f32 + bf16 hi/lo) ----
  const int midx = grp * 16 + pos;
  if (h == 1) {
#pragma unroll
    for (int q = 0; q < 5; ++q)
#pragma unroll
      for (int u = 0; u < 4; ++u) mg[midx][q * 4 + u] = acc[q][u];
  }
  __syncthreads();
  if (h == 0) {
#pragma unroll
    for (int q = 0; q < 5; ++q) {
      const int ch = grp * 5 + q;
      const float a0 = acc[q][0] + mg[midx][q * 4 + 0];
      const float a1 = acc[q][1] + mg[midx][q * 4 + 1];
      const float a2 = acc[q][2] + mg[midx][q * 4 + 2];
      const float a3 = acc[q][3] + mg[midx][q * 4 + 3];
      const float r0v =
          fmaxf(fmaxf(fmaxf(a0, a1), fmaxf(a2, a3)) + bl2[ch], 0.f);
      const int off = imgId * 640 + ch * 16 + pos;
      feats[off] = r0v;
      const unsigned short h0 = f2bf(r0v);
      fh[off] = h0;
      fl[off] = f2bf(r0v - bf2f(h0));
    }
  }
}

// ---- k3m: M = feats @ T^T via bf16x3 MFMA, direct-from-global -------------
// 512 blocks x 256 thr = 4 waves. block: i-frag = bid>>4, j-quad = bid&15.
// wave w owns j-frag = (bid&15)*4 + w; one 16x16 output fragment per wave.
__global__ __launch_bounds__(256) void k3m_gemm(
    const unsigned short* __restrict__ fh, const unsigned short* __restrict__ fl,
    const unsigned short* __restrict__ Th, const unsigned short* __restrict__ Tl,
    float* __restrict__ M) {
  const int tid = threadIdx.x;
  const int w = tid >> 6;
  const int l = tid & 63;
  const int fr = l & 15;
  const int hi = l >> 4;
  const int if0 = blockIdx.x >> 4;            // 0..31
  const int jf = (blockIdx.x & 15) * 4 + w;   // 0..63
  const int abase = (if0 * 16 + fr) * 640 + hi * 8;
  const int bbase = (jf * 16 + fr) * 640 + hi * 8;

  f32x4 acc = (f32x4){0.f, 0.f, 0.f, 0.f};
#pragma unroll
  for (int kk = 0; kk < 20; ++kk) {
    const int ko = kk * 32;
    const bf16x8 aH = *reinterpret_cast<const bf16x8*>(fh + abase + ko);
    const bf16x8 aL = *reinterpret_cast<const bf16x8*>(fl + abase + ko);
    const bf16x8 bH = *reinterpret_cast<const bf16x8*>(Th + bbase + ko);
    const bf16x8 bL = *reinterpret_cast<const bf16x8*>(Tl + bbase + ko);
    acc = __builtin_amdgcn_mfma_f32_16x16x32_bf16(aH, bH, acc, 0, 0, 0);
    acc = __builtin_amdgcn_mfma_f32_16x16x32_bf16(aL, bH, acc, 0, 0, 0);
    acc = __builtin_amdgcn_mfma_f32_16x16x32_bf16(aH, bL, acc, 0, 0, 0);
  }
  // C/D layout: col = lane&15, row = (lane>>4)*4 + reg  [m89-verified]
#pragma unroll
  for (int r = 0; r < 4; ++r) {
    M[(if0 * 16 + hi * 4 + r) * 1024 + jf * 16 + fr] = acc[r];
  }
}

// ---- k4: partial closeness, LDS-staged swizzled j-rows --------------------
__global__ __launch_bounds__(256) void k4_mbd(const float* __restrict__ M,
                                              float* __restrict__ cp) {
  __shared__ float4 jb4[2][4][256];
  const int bid = blockIdx.x;
  const int ig = bid >> 4;
  const int jq = bid & 15;
  const int t = threadIdx.x;
  const int b = t & 63;
  const int g = t >> 6;
  const int i0 = ig * 16 + g * 4;
  const float4* Mf4 = reinterpret_cast<const float4*>(M);

  float4 mi[4][4];
#pragma unroll
  for (int u = 0; u < 4; ++u) {
#pragma unroll
    for (int q = 0; q < 4; ++q) mi[u][q] = Mf4[(i0 + u) * 256 + b * 4 + q];
  }
  const int wslot = (t >> 2) * 4 + ((t & 3) ^ ((t >> 3) & 3));
  {
#pragma unroll
    for (int k = 0; k < 4; ++k)
      jb4[0][k][wslot] = Mf4[(jq * 32 + k) * 256 + t];
  }
  __syncthreads();

  float acc[4] = {0.f, 0.f, 0.f, 0.f};
  const int xr = (b >> 1) & 3;
  for (int c = 0; c < 8; ++c) {
    float4 st[4];
    if (c < 7) {
#pragma unroll
      for (int k = 0; k < 4; ++k)
        st[k] = Mf4[(jq * 32 + (c + 1) * 4 + k) * 256 + t];
    }
    const int cbuf = c & 1;
#pragma unroll
    for (int jj = 0; jj < 4; ++jj) {
      const float4* rowp = jb4[cbuf][jj];
      float4 mj[4];
#pragma unroll
      for (int q = 0; q < 4; ++q) mj[q] = rowp[b * 4 + (q ^ xr)];
#pragma unroll
      for (int u = 0; u < 4; ++u) {
        float dist =
            fabsf(mi[u][0].x - mj[0].x) + fabsf(mi[u][0].y - mj[0].y) +
            fabsf(mi[u][0].z - mj[0].z) + fabsf(mi[u][0].w - mj[0].w) +
            fabsf(mi[u][1].x - mj[1].x) + fabsf(mi[u][1].y - mj[1].y) +
            fabsf(mi[u][1].z - mj[1].z) + fabsf(mi[u][1].w - mj[1].w) +
            fabsf(mi[u][2].x - mj[2].x) + fabsf(mi[u][2].y - mj[2].y) +
            fabsf(mi[u][2].z - mj[2].z) + fabsf(mi[u][2].w - mj[2].w) +
            fabsf(mi[u][3].x - mj[3].x) + fabsf(mi[u][3].y - mj[3].y) +
            fabsf(mi[u][3].z - mj[3].z) + fabsf(mi[u][3].w - mj[3].w);
        acc[u] += __expf(-dist);
      }
    }
    if (c < 7) {
#pragma unroll
      for (int k = 0; k < 4; ++k) jb4[(c + 1) & 1][k][wslot] = st[k];
    }
    __syncthreads();
  }
#pragma unroll
  for (int u = 0; u < 4; ++u)
    cp[(jq * 512 + i0 + u) * 64 + b] = acc[u];
}

// ---- k5: head -------------------------------------------------------------
__global__ __launch_bounds__(256) void k5_head(
    const float* __restrict__ feats, const float* __restrict__ cp,
    const float* __restrict__ w1, const float* __restrict__ b1,
    const float* __restrict__ w2, const float* __restrict__ b2,
    float* __restrict__ out) {
  __shared__ __align__(16) float v[704];
  __shared__ float hb[100];
  const int i = blockIdx.x;
  const int tid = threadIdx.x;
  float4* v4 = reinterpret_cast<float4*>(v);
  if (tid < 160)
    v4[tid] = reinterpret_cast<const float4*>(feats + i * 640)[tid];
  if (tid >= 192) {
    const int bb = tid - 192;
    float s = 0.f;
#pragma unroll
    for (int q = 0; q < 16; ++q) s += cp[(q * 512 + i) * 64 + bb];
    v[640 + bb] = s;
  }
  __syncthreads();
  const int wave = tid >> 6;
  const int lane = tid & 63;
  for (int r = wave; r < 100; r += 4) {
    const float4* wr = reinterpret_cast<const float4*>(w1 + r * 704);
    const float4 wa = wr[lane];
    const float4 wb = wr[lane + 64];
    const float4 va = v4[lane];
    const float4 vb = v4[lane + 64];
    float s = wa.x * va.x + wa.y * va.y + wa.z * va.z + wa.w * va.w +
              wb.x * vb.x + wb.y * vb.y + wb.z * vb.z + wb.w * vb.w;
    if (lane < 48) {
      const float4 wc = wr[lane + 128];
      const float4 vc = v4[lane + 128];
      s += wc.x * vc.x + wc.y * vc.y + wc.z * vc.z + wc.w * vc.w;
    }
#pragma unroll
    for (int off = 32; off; off >>= 1) s += __shfl_xor(s, off);
    if (lane == 0) hb[r] = fmaxf(s + b1[r], 0.f) * w2[r];
  }
  __syncthreads();
  if (tid < 64) {
    float s = hb[tid] + ((tid < 36) ? hb[tid + 64] : 0.f);
#pragma unroll
    for (int off = 32; off; off >>= 1) s += __shfl_xor(s, off);
    if (tid == 0) out[i] = 1.f / (1.f + __expf(-(s + b2[0])));
  }
}

extern "C" void kernel_launch(void* const* d_in, const int* in_sizes, int n_in,
                              void* d_out, int out_size, void* d_ws,
                              size_t ws_size, hipStream_t stream) {
  const float* x   = (const float*)d_in[0];
  const float* c1w = (const float*)d_in[1];
  const float* c1b = (const float*)d_in[2];
  const float* c2w = (const float*)d_in[3];
  const float* c2b = (const float*)d_in[4];
  const float* T   = (const float*)d_in[5];
  const float* f1w = (const float*)d_in[6];
  const float* f1b = (const float*)d_in[7];
  const float* f2w = (const float*)d_in[8];
  const float* f2b = (const float*)d_in[9];
  float* out = (float*)d_out;

  float* feats = (float*)d_ws;                    // 327680 f
  float* M     = feats + 327680;                  // 524288 f
  float* cp    = M + 524288;                      // 524288 f
  float* ws2   = cp + 524288;                     // 32000 f
  unsigned short* fh = (unsigned short*)(ws2 + 32000);  // 327680 u16
  unsigned short* fl = fh + 327680;
  unsigned short* Th = fl + 327680;               // 655360 u16
  unsigned short* Tl = Th + 655360;
  // total ~9.6 MB

  kP_prep<<<2560, 256, 0, stream>>>(c2w, T, ws2, Th, Tl);
  kC_conv<<<512, 256, 0, stream>>>(x, c1w, c1b, ws2, c2b, feats, fh, fl);
  k3m_gemm<<<512, 256, 0, stream>>>(fh, fl, Th, Tl, M);
  k4_mbd<<<512, 256, 0, stream>>>(M, cp);
  k5_head<<<512, 256, 0, stream>>>(feats, cp, f1w, f1b, f2w, f2b, out);
}